// Round 14
// baseline (30.750 us; speedup 1.0000x reference)
//
#include <hip/hip_runtime.h>
#include <math.h>

#define NB 4
#define NN 512
#define ND 128
#define NC 10
#define NT 32
#define NPAIR (NT*(NT+1)/2)       // 528 tile-pairs per batch (upper triangle incl diag)
#define BPB (NPAIR/2)             // 264 blocks per batch (2 waves/block)
#define NBLK_M (NB*BPB)           // 1056 blocks

typedef short    bf16x8 __attribute__((ext_vector_type(8)));
typedef unsigned u32x4  __attribute__((ext_vector_type(4)));
typedef float    f32x4  __attribute__((ext_vector_type(4)));

// pack two f32 into two truncated bf16 (low short = a, high short = b)
static __device__ __forceinline__ unsigned pack_trunc(float a, float b) {
    unsigned ua = __builtin_bit_cast(unsigned, a);
    unsigned ub = __builtin_bit_cast(unsigned, b);
    return (ua >> 16) | (ub & 0xFFFF0000u);
}

// span-dependent half of the epilogue (focal loss + counters); shared softmax
// state (L, e, mx, lgs, inv, pred, v) computed once per unordered pair.
static __device__ __forceinline__ void dir_counts(
    const float (&L)[NC], const float (&e)[NC], float mx, float lgs, float inv,
    int pred, bool v, int sp,
    float& lsum, float& accn, float& tpn, float& tnn, float& fpn)
{
    float lsp = L[0], esp = e[0];
    #pragma unroll
    for (int c = 1; c < NC; ++c) {
        lsp = (sp == c) ? L[c] : lsp;
        esp = (sp == c) ? e[c] : esp;
    }
    const float lp   = (lsp - mx) - lgs;
    const float prob = esp * inv;
    const float om   = 1.f - prob;
    const float lm   = -(om * om) * lp;
    if (v) { lsum += lm; if (pred == sp) accn += 1.f; }
    if (sp > 0) { if (pred == sp) tpn += 1.f; else tnn += 1.f; }
    else if (pred > 0 && v) fpn += 1.f;
}

// Symmetric fused MFMA kernel: logits[i,j,:] == logits[j,i,:] (xx is symmetric),
// so each wave computes ONE upper-triangle 16x16 tile-pair (Ti<=Tj) and runs the
// span epilogue for both (i,j) and (j,i). MFMA count halves vs r13.
// Frag semantics (r9-r13 verified, absmax 256 vs thr 17694):
//   A-frag (g): lane l holds x[row = Ti*16 + (l&15)][d = 32g + 8*(l>>4) + e], e=0..7
//   B-frag (c,g): lane l holds y_c[col = Tj*16 + (l&15)][same d-enumeration]
//   C/D: col = lane&15, row = (lane>>4)*4 + reg
__global__ __launch_bounds__(128) void w2ner_fused(
    const float* __restrict__ x, const int* __restrict__ span,
    const int* __restrict__ seqlen, const float* __restrict__ Wm,
    const float* __restrict__ bias, float* __restrict__ out,
    float* __restrict__ accum)
{
    __shared__ float sRed[2 * 5];
    const int tid = threadIdx.x;
    const int blk = blockIdx.x;
    const int b    = blk / BPB;
    const int mblk = blk % BPB;
    const int wv = tid >> 6, l = tid & 63;
    const int jl = l & 15, kg = l >> 4;

    // wave's tile-pair: m -> (Ti, Tj), Tj >= Ti
    int m = mblk * 2 + wv;
    int Ti = 0;
    while (m >= NT - Ti) { m -= NT - Ti; ++Ti; }
    const int Tj = Ti + m;
    const bool mirror = (Tj > Ti);     // wave-uniform branch

    const int j    = Tj * 16 + jl;     // B col / direct-epilogue col
    const int irow = Ti * 16 + jl;     // A row
    const int ib   = Ti * 16 + kg * 4; // C/D row base
    const int sl = seqlen[b];
    const float* xb = x + (size_t)b * NN * ND;
    const size_t sb = (size_t)b * NN * NN;

    // span prefetch for both directions (hides under the MFMA loop)
    int sp[4], spM[4];
    #pragma unroll
    for (int r = 0; r < 4; ++r)
        sp[r] = span[sb + (size_t)(ib + r) * NN + j];
    if (mirror) {
        #pragma unroll
        for (int r = 0; r < 4; ++r)
            spM[r] = span[sb + (size_t)j * NN + (ib + r)];
    }

    f32x4 acc[NC];
    #pragma unroll
    for (int c = 0; c < NC; ++c) acc[c] = (f32x4){0.f, 0.f, 0.f, 0.f};

    #pragma unroll
    for (int g = 0; g < 4; ++g) {
        const int d0 = 32 * g + 8 * kg;

        // A fragment: x_i exact hi/lo split (truncation)
        float xiv[8];
        *(float4*)&xiv[0] = *(const float4*)(xb + (size_t)irow * ND + d0);
        *(float4*)&xiv[4] = *(const float4*)(xb + (size_t)irow * ND + d0 + 4);
        u32x4 ahw, alw;
        #pragma unroll
        for (int e2 = 0; e2 < 4; ++e2) {
            const float a0 = xiv[2 * e2], a1 = xiv[2 * e2 + 1];
            const unsigned u0 = __builtin_bit_cast(unsigned, a0) & 0xFFFF0000u;
            const unsigned u1 = __builtin_bit_cast(unsigned, a1) & 0xFFFF0000u;
            ahw[e2] = (u0 >> 16) | u1;
            alw[e2] = pack_trunc(a0 - __builtin_bit_cast(float, u0),
                                 a1 - __builtin_bit_cast(float, u1));
        }

        // B fragments: y = x_j * W, rounded once to bf16 (trunc)
        float xjv[8];
        *(float4*)&xjv[0] = *(const float4*)(xb + (size_t)j * ND + d0);
        *(float4*)&xjv[4] = *(const float4*)(xb + (size_t)j * ND + d0 + 4);
        u32x4 yw[NC];
        #pragma unroll
        for (int e2 = 0; e2 < 4; ++e2) {
            float wb[20];   // W rows d0+2e2, d0+2e2+1 (20 contiguous floats)
            const float4* wp = (const float4*)(Wm + (size_t)(d0 + 2 * e2) * NC);
            #pragma unroll
            for (int t5 = 0; t5 < 5; ++t5) *(float4*)&wb[4 * t5] = wp[t5];
            const float x0 = xjv[2 * e2], x1 = xjv[2 * e2 + 1];
            #pragma unroll
            for (int c = 0; c < NC; ++c)
                yw[c][e2] = pack_trunc(x0 * wb[c], x1 * wb[10 + c]);
        }

        const bf16x8 ah = __builtin_bit_cast(bf16x8, ahw);
        const bf16x8 al = __builtin_bit_cast(bf16x8, alw);
        #pragma unroll
        for (int c = 0; c < NC; ++c) {
            const bf16x8 bh = __builtin_bit_cast(bf16x8, yw[c]);
            acc[c] = __builtin_amdgcn_mfma_f32_16x16x32_bf16(ah, bh, acc[c], 0, 0, 0);
            acc[c] = __builtin_amdgcn_mfma_f32_16x16x32_bf16(al, bh, acc[c], 0, 0, 0);
        }
    }

    // epilogue: shared softmax per unordered pair; span half run for both dirs
    float lsum = 0.f, accn = 0.f, tpn = 0.f, tnn = 0.f, fpn = 0.f;
    #pragma unroll
    for (int r = 0; r < 4; ++r) {
        const int i = ib + r;
        float L[NC];
        #pragma unroll
        for (int c = 0; c < NC; ++c) L[c] = acc[c][r] + bias[c];
        int am = 0; float mx = L[0];
        #pragma unroll
        for (int c = 1; c < NC; ++c) { if (L[c] > mx) { mx = L[c]; am = c; } }  // first-occurrence argmax
        float e[NC]; float s = 0.f;
        #pragma unroll
        for (int c = 0; c < NC; ++c) { e[c] = __expf(L[c] - mx); s += e[c]; }
        const float inv = __builtin_amdgcn_rcpf(s);
        const float lgs = __logf(s);
        const bool v = (i < sl) && (j < sl);   // symmetric in (i,j)
        const int pred = v ? am : 0;
        out[sb + (size_t)i * NN + j] = (float)pred;
        dir_counts(L, e, mx, lgs, inv, pred, v, sp[r], lsum, accn, tpn, tnn, fpn);
        if (mirror) {
            out[sb + (size_t)j * NN + i] = (float)pred;   // predict symmetric
            dir_counts(L, e, mx, lgs, inv, pred, v, spM[r], lsum, accn, tpn, tnn, fpn);
        }
    }

    // block reduction (2 waves)
    float vals[5] = { lsum, accn, tpn, tnn, fpn };
    #pragma unroll
    for (int k = 0; k < 5; ++k) {
        float vv = vals[k];
        for (int o = 32; o > 0; o >>= 1) vv += __shfl_down(vv, o);
        vals[k] = vv;
    }
    if (l == 0) {
        #pragma unroll
        for (int k = 0; k < 5; ++k) sRed[wv * 5 + k] = vals[k];
    }
    __syncthreads();
    if (tid < 5) accum[(size_t)blk * 5 + tid] = sRed[tid] + sRed[5 + tid];
}

__global__ __launch_bounds__(256) void w2ner_final(
    const int* __restrict__ seqlen, const float* __restrict__ accum,
    float* __restrict__ out)
{
    __shared__ float sP[4][5];
    const int tid = threadIdx.x;
    float part[5] = {0.f, 0.f, 0.f, 0.f, 0.f};
    for (int r = tid; r < NBLK_M; r += 256) {
        #pragma unroll
        for (int k = 0; k < 5; ++k) part[k] += accum[(size_t)r * 5 + k];
    }
    #pragma unroll
    for (int k = 0; k < 5; ++k) {
        float v = part[k];
        for (int o = 32; o > 0; o >>= 1) v += __shfl_down(v, o);
        part[k] = v;
    }
    const int wave = tid >> 6;
    const int lane = tid & 63;
    if (lane == 0) {
        #pragma unroll
        for (int k = 0; k < 5; ++k) sP[wave][k] = part[k];
    }
    __syncthreads();
    if (tid == 0) {
        float t[5];
        #pragma unroll
        for (int k = 0; k < 5; ++k) t[k] = sP[0][k] + sP[1][k] + sP[2][k] + sP[3][k];
        float s2 = 0.f;
        for (int k = 0; k < NB; ++k) { float s = (float)seqlen[k]; s2 += s * s; }
        const size_t base = (size_t)NB * NN * NN;
        out[base + 0] = t[2];          // tp
        out[base + 1] = t[3];          // tn
        out[base + 2] = t[4];          // fp
        out[base + 3] = t[0] / s2;     // loss
        out[base + 4] = t[1] / s2;     // accuracy
    }
}

extern "C" void kernel_launch(void* const* d_in, const int* in_sizes, int n_in,
                              void* d_out, int out_size, void* d_ws, size_t ws_size,
                              hipStream_t stream) {
    const float* x      = (const float*)d_in[0];
    const int*   span   = (const int*)d_in[1];
    const int*   seqlen = (const int*)d_in[2];
    const float* Wm     = (const float*)d_in[3];
    const float* bias   = (const float*)d_in[4];
    float* out   = (float*)d_out;
    float* accum = (float*)d_ws;   // 1056*5 f32, fully overwritten each launch

    w2ner_fused<<<dim3(NBLK_M), 128, 0, stream>>>(x, span, seqlen, Wm, bias, out, accum);
    w2ner_final<<<1, 256, 0, stream>>>(seqlen, accum, out);
}